// Round 1
// 250.218 us; speedup vs baseline: 1.0261x; 1.0261x over previous
//
#include <hip/hip_runtime.h>
#include <math.h>

#define BB 16
#define HH 512
#define WW 512
#define CC 4

// ---------------------------------------------------------------------------
// Kernel 1: y_s = cumsum_h( 2/(1+exp(-defgrad[...,1])) )  (inclusive, per col)
// LDS-tiled streaming version.
//   grid:  BB * (WW/16) = 512 blocks, 512 threads.
//   Each block owns a 16-col strip of one batch image and walks H in 4 chunks
//   of 128 rows. Per chunk: fully-coalesced float2 loads -> logistic -> LDS;
//   then 32 segments x 4 rows serial-sum out of LDS, segment prefix via LDS,
//   per-column carry ping-pongs across chunks. All global accesses stream.
// ---------------------------------------------------------------------------
#define CS_COLS   16
#define CS_CHUNK  128
#define CS_NCHUNK (HH / CS_CHUNK)      // 4
#define CS_SEGS   32                   // 512 threads / 16 cols
#define CS_SEGH   (CS_CHUNK / CS_SEGS) // 4 rows per segment

__global__ __launch_bounds__(512)
void colscan_kernel(const float2* __restrict__ defgrad, float* __restrict__ ys,
                    int ys_stride) {
    const int wt  = blockIdx.x % (WW / CS_COLS);   // 0..31 col-tile
    const int b   = blockIdx.x / (WW / CS_COLS);
    const int tid = threadIdx.x;

    __shared__ float lds[CS_CHUNK][CS_COLS + 1];   // +1 pad: de-conflict reads
    __shared__ float part[CS_SEGS][CS_COLS];
    __shared__ float carry[2][CS_COLS];

    const int lcol = tid & (CS_COLS - 1);          // load-phase col (== scol)
    const int lrow = tid >> 4;                     // load-phase base row 0..31
    const int scol = tid & (CS_COLS - 1);          // scan-phase col
    const int seg  = tid >> 4;                     // scan-phase segment 0..31
    const int wcol = wt * CS_COLS + scol;

    if (tid < CS_COLS) carry[0][tid] = 0.f;

    const float2* dg = defgrad + (size_t)b * HH * WW;

    for (int c = 0; c < CS_NCHUNK; ++c) {
        // ---- fill: coalesced (4 rows x 128B per wave-load), logistic on the fly
#pragma unroll
        for (int k = 0; k < 4; ++k) {
            const int r = lrow + k * 32;                       // 0..127
            const int grow = c * CS_CHUNK + r;
            float v = dg[(size_t)grow * WW + wt * CS_COLS + lcol].y;
            lds[r][lcol] = 2.0f / (1.0f + expf(-v));
        }
        __syncthreads();

        // ---- per-segment serial sums (LDS reads, values kept in regs)
        float vals[CS_SEGH];
        float s = 0.f;
#pragma unroll
        for (int i = 0; i < CS_SEGH; ++i) {
            vals[i] = lds[seg * CS_SEGH + i][scol];
            s += vals[i];
        }
        part[seg][scol] = s;
        const float cold = carry[c & 1][scol];     // written before last sync
        __syncthreads();

        // ---- exclusive segment prefix + chunk total (broadcast LDS reads)
        float run = cold, tot = cold;
#pragma unroll
        for (int j = 0; j < CS_SEGS; ++j) {
            float v = part[j][scol];
            tot += v;
            if (j < seg) run += v;
        }
        if (seg == 0) carry[(c + 1) & 1][scol] = tot;

        // ---- write inclusive scan values
        const size_t gbase =
            ((size_t)(b * HH + c * CS_CHUNK + seg * CS_SEGH) * WW + wcol);
#pragma unroll
        for (int i = 0; i < CS_SEGH; ++i) {
            run += vals[i];
            ys[(gbase + (size_t)i * WW) * (size_t)ys_stride] = run;
        }
        __syncthreads();                            // lds/part/carry reuse
    }
}

// ---------------------------------------------------------------------------
// Kernel 2: per-row fused — x_s row scan + residual affine + bilinear sample.
// v2: 4 output rows per block (im gather locality: y0/y1 windows of the 4 rows
// overlap -> each im row fetched ~once per block instead of ~3x), plus
// XCD-contiguous block remap so neighboring h-blocks share an XCD L2.
//   grid: BB*HH/4 = 2048 blocks; block: 512 threads (one per column).
// ---------------------------------------------------------------------------
#define RS_ROWS 4

__global__ __launch_bounds__(512)
void rowscan_sample_kernel(const float4* __restrict__ im4,
                           const float2* __restrict__ defgrad,
                           const float*  __restrict__ affine,
                           const float*  __restrict__ ys, int ys_stride,
                           float4* __restrict__ out4,
                           float*  __restrict__ grid3) {
    // bijective XCD swizzle: 2048 % 8 == 0, consecutive logical ids per XCD
    const int nwg = BB * (HH / RS_ROWS);
    const int cpx = nwg / 8;
    const int l   = (blockIdx.x & 7) * cpx + (blockIdx.x >> 3);
    const int hb  = l % (HH / RS_ROWS);
    const int b   = l / (HH / RS_ROWS);
    const int h0  = hb * RS_ROWS;

    const int w    = threadIdx.x;          // 0..511 column
    const int lane = w & 63;
    const int wv   = w >> 6;               // 0..7

    const size_t imgbase  = (size_t)b * HH * WW;
    const size_t rowbase0 = imgbase + (size_t)h0 * WW + w;

    // ---- early independent loads: defgrad.x and ys for all 4 rows
    float dgx[RS_ROWS], ysv[RS_ROWS];
#pragma unroll
    for (int r = 0; r < RS_ROWS; ++r) {
        const size_t pix = rowbase0 + (size_t)r * WW;
        dgx[r] = defgrad[pix].x;
        ysv[r] = ys[pix * (size_t)ys_stride];
    }
#pragma unroll
    for (int r = 0; r < RS_ROWS; ++r)
        dgx[r] = 2.0f / (1.0f + expf(-dgx[r]));

    // ---- 4 simultaneous inclusive block scans (wave scan + LDS combine)
    float x0 = dgx[0], x1 = dgx[1], x2 = dgx[2], x3 = dgx[3];
#pragma unroll
    for (int off = 1; off < 64; off <<= 1) {
        float n0 = __shfl_up(x0, off, 64);
        float n1 = __shfl_up(x1, off, 64);
        float n2 = __shfl_up(x2, off, 64);
        float n3 = __shfl_up(x3, off, 64);
        if (lane >= off) { x0 += n0; x1 += n1; x2 += n2; x3 += n3; }
    }
    __shared__ float wsum[8][RS_ROWS];
    if (lane == 63) {
        wsum[wv][0] = x0; wsum[wv][1] = x1; wsum[wv][2] = x2; wsum[wv][3] = x3;
    }
    __syncthreads();
    float p0 = 0.f, p1 = 0.f, p2 = 0.f, p3 = 0.f;
    for (int j = 0; j < wv; ++j) {          // broadcast reads, free
        p0 += wsum[j][0]; p1 += wsum[j][1]; p2 += wsum[j][2]; p3 += wsum[j][3];
    }
    float xs[RS_ROWS] = { x0 + p0, x1 + p1, x2 + p2, x3 + p3 };

    // ---- residual affine (A = affine + I), uniform per block -> SGPRs
    const float* Ab = affine + b * 9;
    const float a00 = Ab[0] + 1.f, a01 = Ab[1], a02 = Ab[2];
    const float a10 = Ab[3], a11 = Ab[4] + 1.f, a12 = Ab[5];
    const float a20 = Ab[6], a21 = Ab[7], a22 = Ab[8] + 1.f;

    // ---- per-row bilinear sample + stores
#pragma unroll
    for (int r = 0; r < RS_ROWS; ++r) {
        const size_t pix = rowbase0 + (size_t)r * WW;
        const float xg = a00 * xs[r] + a01 * ysv[r] + a02;
        const float yg = a10 * xs[r] + a11 * ysv[r] + a12;
        const float wg = a20 * xs[r] + a21 * ysv[r] + a22;

        const int ix = (int)floorf(xg);
        const int iy = (int)floorf(yg);
        const int cx0 = min(max(ix,     0), WW - 1);
        const int cx1 = min(max(ix + 1, 0), WW - 1);
        const int cy0 = min(max(iy,     0), HH - 1);
        const int cy1 = min(max(iy + 1, 0), HH - 1);
        const float x0f = (float)cx0, x1f = (float)cx1;
        const float y0f = (float)cy0, y1f = (float)cy1;
        const float wa = (x1f - xg) * (y1f - yg);
        const float wb = (x1f - xg) * (yg - y0f);
        const float wc = (xg - x0f) * (y1f - yg);
        const float wd = (xg - x0f) * (yg - y0f);

        const float4 Ia = im4[imgbase + (size_t)cy0 * WW + cx0];
        const float4 Ib = im4[imgbase + (size_t)cy1 * WW + cx0];
        const float4 Ic = im4[imgbase + (size_t)cy0 * WW + cx1];
        const float4 Id = im4[imgbase + (size_t)cy1 * WW + cx1];

        float4 o;
        o.x = wa * Ia.x + wb * Ib.x + wc * Ic.x + wd * Id.x;
        o.y = wa * Ia.y + wb * Ib.y + wc * Ic.y + wd * Id.y;
        o.z = wa * Ia.z + wb * Ib.z + wc * Ic.z + wd * Id.z;
        o.w = wa * Ia.w + wb * Ib.w + wc * Ic.w + wd * Id.w;
        out4[pix] = o;

        // grid3 (thread owns grid3[3*pix .. 3*pix+2]; fallback ysv already read)
        grid3[pix * 3 + 0] = xg;
        grid3[pix * 3 + 1] = yg;
        grid3[pix * 3 + 2] = wg;
    }
}

extern "C" void kernel_launch(void* const* d_in, const int* in_sizes, int n_in,
                              void* d_out, int out_size, void* d_ws, size_t ws_size,
                              hipStream_t stream) {
    const float* im      = (const float*)d_in[0];
    const float* defgrad = (const float*)d_in[1];
    const float* affine  = (const float*)d_in[2];

    float* out   = (float*)d_out;
    float* grid3 = out + (size_t)BB * HH * WW * CC;

    const size_t ys_bytes = (size_t)BB * HH * WW * sizeof(float);
    float* ys;
    int ys_stride;
    if (ws_size >= ys_bytes) {             // planar scratch (preferred)
        ys = (float*)d_ws;
        ys_stride = 1;
    } else {                               // stash in grid3[...,1] slot (race-free)
        ys = grid3 + 1;
        ys_stride = 3;
    }

    colscan_kernel<<<BB * (WW / CS_COLS), 512, 0, stream>>>(
        (const float2*)defgrad, ys, ys_stride);

    rowscan_sample_kernel<<<BB * (HH / RS_ROWS), 512, 0, stream>>>(
        (const float4*)im, (const float2*)defgrad, affine,
        ys, ys_stride, (float4*)out, grid3);
}